// Round 3
// baseline (498.545 us; speedup 1.0000x reference)
//
#include <hip/hip_runtime.h>
#include <hip/hip_bf16.h>

#define B 64
#define N 1025
#define C 768
#define H 12
#define HD 64
#define TILES 17   // 64-row tiles per batch

__device__ __forceinline__ float wave_reduce_add(float v) {
    #pragma unroll
    for (int m = 1; m < 64; m <<= 1) v += __shfl_xor(v, m, 64);
    return v;
}

// ---------------------------------------------------------------------------
// k_qproj: q[b][c] = 0.125 * (cls[b] . qW[c,:] + qb[c])
// grid (16 btiles, 48 ctiles of 16), block 256 (4 waves). Wave w = batch.
// ---------------------------------------------------------------------------
__global__ __launch_bounds__(256) void k_qproj(const float* __restrict__ x,
                                               const float* __restrict__ qW,
                                               const float* __restrict__ qb,
                                               float* __restrict__ qout) {
    __shared__ float cls[4 * C];
    int bt = blockIdx.x, ct = blockIdx.y, tid = threadIdx.x;
    for (int i = tid; i < 768; i += 256) {   // 768 float4 = 4 rows x 192
        int bl = i / 192, c4 = i % 192;
        ((float4*)cls)[i] = ((const float4*)(x + (size_t)(bt * 4 + bl) * N * C))[c4];
    }
    __syncthreads();
    int w = tid >> 6, lane = tid & 63;
    int b = bt * 4 + w;
    const float* clsrow = &cls[w * C];
    for (int cl = 0; cl < 16; ++cl) {
        int c = ct * 16 + cl;
        const float4* wr = (const float4*)(qW + (size_t)c * C + lane * 12);
        const float4* xr = (const float4*)(clsrow + lane * 12);
        float acc = 0.f;
        #pragma unroll
        for (int s = 0; s < 3; ++s) {
            float4 a = wr[s], v = xr[s];
            acc += a.x * v.x + a.y * v.y + a.z * v.z + a.w * v.w;
        }
        acc = wave_reduce_add(acc);
        if (lane == 0) qout[b * C + c] = 0.125f * (acc + qb[c]);
    }
}

// ---------------------------------------------------------------------------
// k_qk: qk[b][h][c'] = sum_{i<64} q[b][h*64+i] * kW[h*64+i][c']
//       qkb[b][h]    = sum_{i<64} q[b][h*64+i] * kb[h*64+i]
// grid (16 btiles, 12 heads), block 256.
// ---------------------------------------------------------------------------
__global__ __launch_bounds__(256) void k_qk(const float* __restrict__ q,
                                            const float* __restrict__ kW,
                                            const float* __restrict__ kb,
                                            float* __restrict__ qk,
                                            float* __restrict__ qkb) {
    int bt = blockIdx.x, h = blockIdx.y, tid = threadIdx.x;
    if (tid < 192) {
        float4 acc[4] = {};
        #pragma unroll 4
        for (int i = 0; i < HD; ++i) {
            int row = h * HD + i;
            float4 kv = *(const float4*)(kW + (size_t)row * C + tid * 4);
            #pragma unroll
            for (int bl = 0; bl < 4; ++bl) {
                float qv = q[(bt * 4 + bl) * C + row];  // uniform -> s_load
                acc[bl].x += qv * kv.x; acc[bl].y += qv * kv.y;
                acc[bl].z += qv * kv.z; acc[bl].w += qv * kv.w;
            }
        }
        #pragma unroll
        for (int bl = 0; bl < 4; ++bl) {
            int b = bt * 4 + bl;
            *(float4*)(qk + ((size_t)b * H + h) * C + tid * 4) = acc[bl];
        }
    }
    int w = tid >> 6, lane = tid & 63;
    int b = bt * 4 + w;
    float v = q[b * C + h * HD + lane] * kb[h * HD + lane];
    v = wave_reduce_add(v);
    if (lane == 0) qkb[b * H + h] = v;
}

// ---------------------------------------------------------------------------
// k_att (scores + mix1 + exp + unnormalized PV, single x pass):
//   s[h][n] = x[b,n,:].qk[b,h,:] + qkb ; a1 = s + w1W@s + w1b ; e = exp(a1)
//   ype[t][b][h][c] = sum_{n in tile} e[h][n] x[n][c]   (bf16)
//   ypx[t][b][c]    = sum_{n in tile} x[n][c]           (fp32)
//   sstat[b][t][h]  = sum_{n in tile} e[h][n]
// Normalization /S and mix2 are linear -> deferred to k_combine.
// grid (17, 64), block 256. qs LDS reused: qk (36KB) -> raw scores -> e.
// ---------------------------------------------------------------------------
__global__ __launch_bounds__(256) void k_att(const float* __restrict__ x,
                                             const float* __restrict__ qk,
                                             const float* __restrict__ qkbias,
                                             const float* __restrict__ w1W,
                                             const float* __restrict__ w1b,
                                             __hip_bfloat16* __restrict__ ype,
                                             float* __restrict__ ypx,
                                             float* __restrict__ sstat) {
    __shared__ float qs[12 * C];   // 36 KB
    __shared__ float w1s[144], w1bs[12], qbs[12];
    int tile = blockIdx.x, b = blockIdx.y, tid = threadIdx.x;
    const float4* qksrc = (const float4*)(qk + (size_t)b * H * C);
    for (int i = tid; i < 2304; i += 256) ((float4*)qs)[i] = qksrc[i];
    if (tid < 144) w1s[tid] = w1W[tid];
    if (tid < 12)  { w1bs[tid] = w1b[tid]; qbs[tid] = qkbias[b * 12 + tid]; }

    int lane = tid & 63, w = tid >> 6;
    int c16 = lane & 15, r = lane >> 4;
    int rowbase = tile * 64 + w * 16 + r * 4;
    const float* xb = x + (size_t)b * N * C;
    const float4 z4 = make_float4(0.f, 0.f, 0.f, 0.f);

    // preload step 0 x before the barrier (overlaps qk staging)
    float4 xcur[4], xnxt[4];
    #pragma unroll
    for (int j = 0; j < 4; ++j) {
        int row = rowbase + j;
        xcur[j] = (row < N) ? *(const float4*)(xb + (size_t)row * C + c16 * 4) : z4;
    }
    __syncthreads();

    // phase A: 12 steps of 64 cols, double-buffered x prefetch
    float acc[4][12] = {};
    for (int cc = 0; cc < 12; ++cc) {
        if (cc < 11) {
            int cn = (cc + 1) * 64 + c16 * 4;
            #pragma unroll
            for (int j = 0; j < 4; ++j) {
                int row = rowbase + j;
                xnxt[j] = (row < N) ? *(const float4*)(xb + (size_t)row * C + cn) : z4;
            }
        }
        int cq = cc * 64 + c16 * 4;
        #pragma unroll
        for (int h = 0; h < 12; ++h) {
            float4 q0 = *(const float4*)(qs + h * C + cq);
            #pragma unroll
            for (int j = 0; j < 4; ++j)
                acc[j][h] += xcur[j].x * q0.x + xcur[j].y * q0.y +
                             xcur[j].z * q0.z + xcur[j].w * q0.w;
        }
        if (cc < 11) {
            #pragma unroll
            for (int j = 0; j < 4; ++j) xcur[j] = xnxt[j];
        }
    }
    #pragma unroll
    for (int j = 0; j < 4; ++j)
        #pragma unroll
        for (int h = 0; h < 12; ++h) {
            float v = acc[j][h];
            v += __shfl_xor(v, 1); v += __shfl_xor(v, 2);
            v += __shfl_xor(v, 4); v += __shfl_xor(v, 8);
            acc[j][h] = v;
        }
    __syncthreads();             // all qs(qk) reads done -> safe to reuse
    if (c16 == 0) {
        #pragma unroll
        for (int j = 0; j < 4; ++j)
            #pragma unroll
            for (int h = 0; h < 12; ++h)
                qs[(w * 16 + r * 4 + j) * 12 + h] = acc[j][h];
    }
    __syncthreads();
    if (tid < 64) {              // wave 0: mix1 + exp + tile sums
        int row = tile * 64 + tid;
        bool valid = row < N;
        float s_[12], e[12];
        #pragma unroll
        for (int h = 0; h < 12; ++h) s_[h] = qs[tid * 12 + h] + qbs[h];
        #pragma unroll
        for (int g = 0; g < 12; ++g) {
            float a = s_[g] + w1bs[g];
            #pragma unroll
            for (int h = 0; h < 12; ++h) a += w1s[g * 12 + h] * s_[h];
            e[g] = valid ? __expf(a) : 0.f;   // scores O(+-2): no max needed
        }
        #pragma unroll
        for (int g = 0; g < 12; ++g) qs[tid * 12 + g] = e[g];
        #pragma unroll
        for (int g = 0; g < 12; ++g) {
            float sg = wave_reduce_add(e[g]);
            if (tid == 0) sstat[((size_t)b * TILES + tile) * 12 + g] = sg;
        }
    }
    __syncthreads();

    // phase B: PV accumulate over the tile's 64 rows (x re-read is L2-hot).
    // thread owns cols {tid, tid+256, tid+512}.
    float pacc[12][3] = {};
    float xs[3] = {0.f, 0.f, 0.f};
    int nv = N - tile * 64; if (nv > 64) nv = 64;
    for (int n0 = 0; n0 < 64; n0 += 4) {
        float xv[4][3];
        #pragma unroll
        for (int u = 0; u < 4; ++u) {
            int n = n0 + u;
            const float* xr = xb + (size_t)(tile * 64 + n) * C + tid;
            bool val = n < nv;
            xv[u][0] = val ? xr[0]   : 0.f;
            xv[u][1] = val ? xr[256] : 0.f;
            xv[u][2] = val ? xr[512] : 0.f;
        }
        #pragma unroll
        for (int u = 0; u < 4; ++u) {
            const float* er = qs + (n0 + u) * 12;   // broadcast LDS read
            xs[0] += xv[u][0]; xs[1] += xv[u][1]; xs[2] += xv[u][2];
            #pragma unroll
            for (int h = 0; h < 12; ++h) {
                float ev = er[h];
                pacc[h][0] += ev * xv[u][0];
                pacc[h][1] += ev * xv[u][1];
                pacc[h][2] += ev * xv[u][2];
            }
        }
    }
    size_t base = (size_t)tile * B + b;
    #pragma unroll
    for (int h = 0; h < 12; ++h) {
        __hip_bfloat16* dst = ype + (base * 12 + h) * C + tid;
        dst[0]   = __float2bfloat16(pacc[h][0]);
        dst[256] = __float2bfloat16(pacc[h][1]);
        dst[512] = __float2bfloat16(pacc[h][2]);
    }
    float* xdst = ypx + base * C + tid;
    xdst[0] = xs[0]; xdst[256] = xs[1]; xdst[512] = xs[2];
}

// ---------------------------------------------------------------------------
// k_combine: S_h = sum_t sstat; P_h(c) = sum_t ype / S_h; X(c) = sum_t ypx;
// ybar[b][g][c] = P_g + w2W@P + w2b_g * X.   grid (3 cgroups, 64 b), 256.
// ---------------------------------------------------------------------------
__global__ __launch_bounds__(256) void k_combine(const __hip_bfloat16* __restrict__ ype,
                                                 const float* __restrict__ ypx,
                                                 const float* __restrict__ sstat,
                                                 const float* __restrict__ w2W,
                                                 const float* __restrict__ w2b,
                                                 float* __restrict__ ybar) {
    __shared__ float w2s[144], w2bs[12], ish[12];
    int cg = blockIdx.x, b = blockIdx.y, tid = threadIdx.x;
    if (tid < 144) w2s[tid] = w2W[tid];
    if (tid < 12) {
        w2bs[tid] = w2b[tid];
        float S = 0.f;
        #pragma unroll
        for (int t = 0; t < TILES; ++t) S += sstat[((size_t)b * TILES + t) * 12 + tid];
        ish[tid] = 1.f / S;
    }
    __syncthreads();
    int c = cg * 256 + tid;
    float P[12] = {};
    float X = 0.f;
    for (int t = 0; t < TILES; ++t) {
        size_t base = (size_t)t * B + b;
        const __hip_bfloat16* src = ype + base * 12 * C + c;
        #pragma unroll
        for (int h = 0; h < 12; ++h) P[h] += __bfloat162float(src[h * C]);
        X += ypx[base * C + c];
    }
    #pragma unroll
    for (int h = 0; h < 12; ++h) P[h] *= ish[h];
    #pragma unroll
    for (int g = 0; g < 12; ++g) {
        float a = P[g] + w2bs[g] * X;
        #pragma unroll
        for (int h = 0; h < 12; ++h) a += w2s[g * 12 + h] * P[h];
        ybar[((size_t)b * 12 + g) * C + c] = a;
    }
}

// ---------------------------------------------------------------------------
// k_zproj: z[b][c] = ybar[b,h(c),:] . vW[c,:] + vb[c]*sv,
// sv = 1 + rowsum(w2W)[h] + N*w2b[h] (softmax rows sum to 1 -> closed form).
// grid (16 btiles, 12 heads), block 256.
// ---------------------------------------------------------------------------
__global__ __launch_bounds__(256) void k_zproj(const float* __restrict__ ybar,
                                               const float* __restrict__ vW,
                                               const float* __restrict__ vb,
                                               const float* __restrict__ w2W,
                                               const float* __restrict__ w2b,
                                               float* __restrict__ z) {
    __shared__ float ys[4 * C];
    int bt = blockIdx.x, h = blockIdx.y, tid = threadIdx.x;
    for (int i = tid; i < 768; i += 256) {   // 4 rows x 192 float4
        int bl = i / 192, c4 = i % 192;
        int b = bt * 4 + bl;
        ((float4*)ys)[i] = ((const float4*)(ybar + ((size_t)b * 12 + h) * C))[c4];
    }
    __syncthreads();
    float sv = 1.f + 1025.f * w2b[h];
    #pragma unroll
    for (int j = 0; j < 12; ++j) sv += w2W[h * 12 + j];
    int w = tid >> 6, lane = tid & 63;
    int b = bt * 4 + w;
    const float* yrow = &ys[w * C];
    for (int cl = 0; cl < 64; ++cl) {
        int c = h * 64 + cl;
        const float4* wr = (const float4*)(vW + (size_t)c * C + lane * 12);
        const float4* yr = (const float4*)(yrow + lane * 12);
        float acc = 0.f;
        #pragma unroll
        for (int s = 0; s < 3; ++s) {
            float4 a = wr[s], v = yr[s];
            acc += a.x * v.x + a.y * v.y + a.z * v.z + a.w * v.w;
        }
        acc = wave_reduce_add(acc);
        if (lane == 0) z[b * C + c] = acc + vb[c] * sv;
    }
}

// ---------------------------------------------------------------------------
// k_out: out[b][c] = z[b,:] . projW[c,:] + projb[c]
// grid (16 btiles, 48 ctiles of 16), block 256.
// ---------------------------------------------------------------------------
__global__ __launch_bounds__(256) void k_out(const float* __restrict__ z,
                                             const float* __restrict__ pW,
                                             const float* __restrict__ pb,
                                             float* __restrict__ out) {
    __shared__ float zs[4 * C];
    int bt = blockIdx.x, ct = blockIdx.y, tid = threadIdx.x;
    for (int i = tid; i < 768; i += 256)
        ((float4*)zs)[i] = ((const float4*)(z + (size_t)bt * 4 * C))[i];
    __syncthreads();
    int w = tid >> 6, lane = tid & 63;
    int b = bt * 4 + w;
    for (int cl = 0; cl < 16; ++cl) {
        int c = ct * 16 + cl;
        const float4* wr = (const float4*)(pW + (size_t)c * C + lane * 12);
        const float4* zr = (const float4*)(zs + w * C + lane * 12);
        float acc = 0.f;
        #pragma unroll
        for (int s = 0; s < 3; ++s) {
            float4 a = wr[s], v = zr[s];
            acc += a.x * v.x + a.y * v.y + a.z * v.z + a.w * v.w;
        }
        acc = wave_reduce_add(acc);
        if (lane == 0) out[b * C + c] = acc + pb[c];
    }
}

extern "C" void kernel_launch(void* const* d_in, const int* in_sizes, int n_in,
                              void* d_out, int out_size, void* d_ws, size_t ws_size,
                              hipStream_t stream) {
    const float* x    = (const float*)d_in[0];
    const float* qW   = (const float*)d_in[1];
    const float* qb   = (const float*)d_in[2];
    const float* kW   = (const float*)d_in[3];
    const float* kb   = (const float*)d_in[4];
    const float* vW   = (const float*)d_in[5];
    const float* vb   = (const float*)d_in[6];
    const float* w1W  = (const float*)d_in[7];
    const float* w1b  = (const float*)d_in[8];
    const float* w2W  = (const float*)d_in[9];
    const float* w2b  = (const float*)d_in[10];
    const float* pW   = (const float*)d_in[11];
    const float* pb   = (const float*)d_in[12];
    float* out = (float*)d_out;

    float* ws    = (float*)d_ws;
    float* qk    = ws + 0;        // 64*12*768 = 589824 (later: ybar)
    float* qkb   = ws + 589824;   // 768
    float* q     = ws + 590592;   // 49152 (later: z)
    float* sstat = ws + 639744;   // 64*17*12 = 13056
    float* ypx   = ws + 652800;   // 17*64*768 = 835584 (fp32 x-sums)
    __hip_bfloat16* ype = (__hip_bfloat16*)(ws + 1488384); // 17*64*12*768 bf16 = 5013504 slots
    float* ybar  = qk;            // qk dead after k_att
    float* z     = q;             // q dead after k_qk
    // total 6501888 floats = 26.0 MB

    k_qproj  <<<dim3(16, 48), 256, 0, stream>>>(x, qW, qb, q);
    k_qk     <<<dim3(16, 12), 256, 0, stream>>>(q, kW, kb, qk, qkb);
    k_att    <<<dim3(17, 64), 256, 0, stream>>>(x, qk, qkb, w1W, w1b, ype, ypx, sstat);
    k_combine<<<dim3(3, 64),  256, 0, stream>>>(ype, ypx, sstat, w2W, w2b, ybar);
    k_zproj  <<<dim3(16, 12), 256, 0, stream>>>(ybar, vW, vb, w2W, w2b, z);
    k_out    <<<dim3(16, 48), 256, 0, stream>>>(z, pW, pb, out);
}